// Round 5
// baseline (531.720 us; speedup 1.0000x reference)
//
#include <hip/hip_runtime.h>
#include <stdint.h>

#define NROWS 1024
#define NCOLS 16384
#define NRB 64        // row tiles (16 rows each)
#define NCB 16        // col tiles (1024 cols each)
#define TROWS 16      // rows per tile
#define NROUNDS 2
#define NBLK (NRB * NCB)   // 1024 blocks = 4/CU x 256 CU, all co-resident:
                           // launch_bounds(256,4) -> 4 blocks/CU guaranteed,
                           // plain launch (graph-capturable, round-4 verified).

#define NLEAF 64
#define LEAFSZ (NBLK / NLEAF)   // 16 arrivals per leaf

typedef unsigned long long u64;
typedef unsigned int u32;

// Persistent device state. Everything is written each call before being read.
__device__ u64 g_rowpart[NCB * NROWS];         // per col-tile row maxima
__device__ u64 g_colpart[(size_t)NRB * NCOLS]; // per row-tile col maxima (8 MB)
__device__ u64 g_rowbest[NROWS];               // key: (sortable<<32)|(NCOLS-1-col)
__device__ int g_col_used[NCOLS];
__device__ int g_row_assigned[NROWS];
__device__ int g_rem[2][NROWS];                // double-buffered remaining lists
__device__ int g_cnt[NROUNDS + 1];             // list counts per round

// Monotone (never-reset) tree-barrier counters; valid across launches/replays.
__device__ int g_bar_leaf[NLEAF * 32];         // one 128B line per leaf
__device__ int g_bar_root;
__device__ int g_bar_gen;

// ---- RELAXED agent-scope accessors: device-coherent via MALL, NO cache
// maintenance ops (round-3 confirmed: removing wbl2/inv storms = 885->82us).
__device__ __forceinline__ u64 ald64(const u64* p) {
    return __hip_atomic_load((u64*)p, __ATOMIC_RELAXED, __HIP_MEMORY_SCOPE_AGENT);
}
__device__ __forceinline__ void ast64(u64* p, u64 v) {
    __hip_atomic_store(p, v, __ATOMIC_RELAXED, __HIP_MEMORY_SCOPE_AGENT);
}
__device__ __forceinline__ int ald32(const int* p) {
    return __hip_atomic_load((int*)p, __ATOMIC_RELAXED, __HIP_MEMORY_SCOPE_AGENT);
}
__device__ __forceinline__ void ast32(int* p, int v) {
    __hip_atomic_store(p, v, __ATOMIC_RELAXED, __HIP_MEMORY_SCOPE_AGENT);
}
__device__ __forceinline__ int aadd32(int* p, int v) {
    return __hip_atomic_fetch_add(p, v, __ATOMIC_RELAXED, __HIP_MEMORY_SCOPE_AGENT);
}

// Fence-free grid barrier (round-3/4 proven). All threads drain vmem ->
// syncthreads -> tid0 arrives via monotone leaf->root->gen counters at MALL.
__device__ __forceinline__ void grid_barrier(int bid, int tid) {
    asm volatile("s_waitcnt vmcnt(0)" ::: "memory");   // all threads drain
    __syncthreads();
    if (tid == 0) {
        int gen = ald32(&g_bar_gen);
        asm volatile("s_waitcnt vmcnt(0)" ::: "memory");  // snapshot bound
        int leaf = (bid & (NLEAF - 1)) * 32;
        int v = aadd32(&g_bar_leaf[leaf], 1);
        if ((v & (LEAFSZ - 1)) == LEAFSZ - 1) {           // leaf complete
            int u = aadd32(&g_bar_root, 1);
            if ((u & (NLEAF - 1)) == NLEAF - 1) {         // grid complete
                aadd32(&g_bar_gen, 1);
            }
        }
        while (ald32(&g_bar_gen) == gen) {
            __builtin_amdgcn_s_sleep(8);   // ~512cy nap, no cache ops
        }
    }
    __syncthreads();
    asm volatile("" ::: "memory");
}

// Monotone float32 -> uint32 mapping (preserves <):
__device__ __forceinline__ u32 fsort(float x) {
    u32 u = __float_as_uint(x);
    return u ^ ((u32)((int)u >> 31) | 0x80000000u);
}

__device__ __forceinline__ u64 wave_reduce_max(u64 v) {
    for (int off = 32; off; off >>= 1) {
        u64 o = __shfl_down(v, off);
        if (o > v) v = o;
    }
    return v;   // valid in lane 0
}

// blockDim == 256 (4 waves)
__device__ __forceinline__ u64 block_reduce_max(u64 v, u64* s_part) {
    v = wave_reduce_max(v);
    int wave = threadIdx.x >> 6;
    if ((threadIdx.x & 63) == 0) s_part[wave] = v;
    __syncthreads();
    u64 b = s_part[0];
    for (int w = 1; w < 4; w++) if (s_part[w] > b) b = s_part[w];
    __syncthreads();
    return b;
}

// Per-row scan helper: fold 4 cols into col-maxima (b0..b3, keyed by row) and
// produce the row-max candidate m (keyed by col).
__device__ __forceinline__ void scan_row(float4 v, int r, int c0,
                                         u64& b0, u64& b1, u64& b2, u64& b3,
                                         u64& m) {
    u32 rk = (u32)(NROWS - 1 - r);
    u64 k0 = ((u64)fsort(v.x) << 32) | rk; if (k0 > b0) b0 = k0;
    u64 k1 = ((u64)fsort(v.y) << 32) | rk; if (k1 > b1) b1 = k1;
    u64 k2 = ((u64)fsort(v.z) << 32) | rk; if (k2 > b2) b2 = k2;
    u64 k3 = ((u64)fsort(v.w) << 32) | rk; if (k3 > b3) b3 = k3;
    u64 m0 = ((u64)fsort(v.x) << 32) | (u32)(NCOLS - 1 - (c0 + 0));
    u64 m1 = ((u64)fsort(v.y) << 32) | (u32)(NCOLS - 1 - (c0 + 1));
    u64 m2 = ((u64)fsort(v.z) << 32) | (u32)(NCOLS - 1 - (c0 + 2));
    u64 m3 = ((u64)fsort(v.w) << 32) | (u32)(NCOLS - 1 - (c0 + 3));
    m = m0; if (m1 > m) m = m1; if (m2 > m) m = m2; if (m3 > m) m = m3;
}

// ---------- Phase 1: tile scan. 16 rows x 1024 cols per block ----------
// Rows processed in groups of 4: 4 float4 loads issued together (memory ILP)
// and 4 INDEPENDENT interleaved shuffle-reduce chains (the round-4 version's
// per-row 6-step dependent u64 shfl chain ~400cy x16 rows was the scan's
// serial latency core; interleaving pipelines it ~3x).
__device__ __forceinline__ void phase_scan(const float* __restrict__ cost,
                                           int fb, int tid, u64 (*s_row)[4]) {
    const int cb = fb & (NCB - 1);
    const int rb = fb >> 4;
    const int cbase = cb * 1024;
    const int r0 = rb * TROWS;
    const int c0 = cbase + tid * 4;
    const int wv = tid >> 6, lane = tid & 63;

    if (rb == 0) {     // init: each cb-block zeroes its col_used slice (MALL)
        ast64((u64*)(g_col_used + cbase) + tid * 2 + 0, 0ULL);
        ast64((u64*)(g_col_used + cbase) + tid * 2 + 1, 0ULL);
        if (cb == 0 && tid <= NROUNDS) ast32(&g_cnt[tid], 0);
    }

    u64 b0 = 0, b1 = 0, b2 = 0, b3 = 0;
    for (int g = 0; g < TROWS; g += 4) {
        const float* base = cost + (size_t)(r0 + g) * NCOLS + c0;
        float4 v0 = *(const float4*)(base);
        float4 v1 = *(const float4*)(base + NCOLS);
        float4 v2 = *(const float4*)(base + 2 * NCOLS);
        float4 v3 = *(const float4*)(base + 3 * NCOLS);
        u64 m0, m1, m2, m3;
        scan_row(v0, r0 + g + 0, c0, b0, b1, b2, b3, m0);
        scan_row(v1, r0 + g + 1, c0, b0, b1, b2, b3, m1);
        scan_row(v2, r0 + g + 2, c0, b0, b1, b2, b3, m2);
        scan_row(v3, r0 + g + 3, c0, b0, b1, b2, b3, m3);
        for (int off = 32; off; off >>= 1) {   // 4 interleaved chains
            u64 o0 = __shfl_down(m0, off); if (o0 > m0) m0 = o0;
            u64 o1 = __shfl_down(m1, off); if (o1 > m1) m1 = o1;
            u64 o2 = __shfl_down(m2, off); if (o2 > m2) m2 = o2;
            u64 o3 = __shfl_down(m3, off); if (o3 > m3) m3 = o3;
        }
        if (lane == 0) {
            s_row[g + 0][wv] = m0;
            s_row[g + 1][wv] = m1;
            s_row[g + 2][wv] = m2;
            s_row[g + 3][wv] = m3;
        }
    }
    size_t cp = (size_t)rb * NCOLS + c0;
    ast64(&g_colpart[cp + 0], b0);
    ast64(&g_colpart[cp + 1], b1);
    ast64(&g_colpart[cp + 2], b2);
    ast64(&g_colpart[cp + 3], b3);
    __syncthreads();
    if (tid < TROWS) {
        u64 m = s_row[tid][0];
        if (s_row[tid][1] > m) m = s_row[tid][1];
        if (s_row[tid][2] > m) m = s_row[tid][2];
        if (s_row[tid][3] > m) m = s_row[tid][3];
        ast64(&g_rowpart[cb * NROWS + (r0 + tid)], m);
    }
}

// ---------- Phase 2: mutual-best commit. One wave per row r ----------
__device__ __forceinline__ void phase_commit(int* __restrict__ out, int r, int lane) {
    u64 v = ald64(&g_rowpart[(lane & 15) * NROWS + r]);
    u64 key = wave_reduce_max(v);
    key = __shfl(key, 0);                       // broadcast
    int c = NCOLS - 1 - (int)(key & 0xFFFFFFFFu);

    u64 cp = ald64(&g_colpart[(size_t)lane * NCOLS + c]);
    u64 colmax = wave_reduce_max(cp);           // lane 0

    if (lane == 0) {
        ast64(&g_rowbest[r], key);
        out[r] = r;                             // identity row indices
        u64 mk = (key & 0xFFFFFFFF00000000ULL) | (u32)(NROWS - 1 - r);
        if (colmax == mk) {                     // mutual best -> commit
            ast32(&g_col_used[c], 1);
            ast32(&g_row_assigned[r], 1);
            out[NROWS + r] = c;
        } else {
            ast32(&g_row_assigned[r], 0);
            int p = aadd32(&g_cnt[0], 1);
            ast32(&g_rem[0][p], r);
        }
    }
}

// ---------- Per-round phase (256 threads, block = row r) ----------
__device__ __forceinline__ void phase_round(const float* __restrict__ cost,
                                            int* __restrict__ out, int t, int r,
                                            int tid, u64* s_part) {
    if (ald32(&g_row_assigned[r])) return;   // uniform across block

    u64 key = ald64(&g_rowbest[r]);
    int c = NCOLS - 1 - (int)(key & 0xFFFFFFFFu);
    if (ald32(&g_col_used[c])) {      // stale -> rescan excluding used cols
        u64 best = 0ULL;
        const float4* row = (const float4*)(cost + (size_t)r * NCOLS);
        const u64* used = (const u64*)g_col_used;
        for (int k = tid; k < NCOLS / 4; k += 256) {
            float4 v = row[k];
            u64 w0 = ald64(&used[k * 2 + 0]);   // cols c0, c0+1
            u64 w1 = ald64(&used[k * 2 + 1]);   // cols c0+2, c0+3
            int c0 = k * 4;
            if (!(u32)w0)         { u64 kk = ((u64)fsort(v.x) << 32) | (u32)(NCOLS - 1 - (c0 + 0)); if (kk > best) best = kk; }
            if (!(u32)(w0 >> 32)) { u64 kk = ((u64)fsort(v.y) << 32) | (u32)(NCOLS - 1 - (c0 + 1)); if (kk > best) best = kk; }
            if (!(u32)w1)         { u64 kk = ((u64)fsort(v.z) << 32) | (u32)(NCOLS - 1 - (c0 + 2)); if (kk > best) best = kk; }
            if (!(u32)(w1 >> 32)) { u64 kk = ((u64)fsort(v.w) << 32) | (u32)(NCOLS - 1 - (c0 + 3)); if (kk > best) best = kk; }
        }
        key = block_reduce_max(best, s_part);
        if (tid == 0) ast64(&g_rowbest[r], key);
        c = NCOLS - 1 - (int)(key & 0xFFFFFFFFu);
    }

    int n = ald32(&g_cnt[t]);
    const int* list = g_rem[t & 1];
    u64 mine = (key & 0xFFFFFFFF00000000ULL) | (u32)(NROWS - 1 - r);
    u64 mx = 0ULL;
    for (int j = tid; j < n; j += 256) {
        int rj = ald32(&list[j]);
        if (rj != r) {
            float x = cost[(size_t)rj * NCOLS + c];
            u64 kj = ((u64)fsort(x) << 32) | (u32)(NROWS - 1 - rj);
            if (kj > mx) mx = kj;
        }
    }
    mx = block_reduce_max(mx, s_part);
    if (tid == 0) {
        if (mine > mx) {              // unique max at col c among survivors
            ast32(&g_col_used[c], 1);
            ast32(&g_row_assigned[r], 1);
            out[NROWS + r] = c;
        } else {
            int p = aadd32(&g_cnt[t + 1], 1);
            ast32(&g_rem[(t + 1) & 1][p], r);
        }
    }
}

// ---------- Final serial cleanup, single block of 256 ----------
__device__ __forceinline__ void phase_finish(const float* __restrict__ cost,
                                             int* __restrict__ out, int tid,
                                             int (*s_rem)[NROWS], u64* s_part,
                                             int* s_nn) {
    if (tid == 0) s_nn[0] = ald32(&g_cnt[NROUNDS]);
    __syncthreads();
    int n = s_nn[0];
    if (n == 0) return;
    for (int i = tid; i < n; i += 256) s_rem[0][i] = ald32(&g_rem[NROUNDS & 1][i]);
    __syncthreads();
    int cur = 0;
    while (n > 0) {
        for (int i = 0; i < n; i++) {
            int r = s_rem[cur][i];
            u64 key = ald64(&g_rowbest[r]);
            int c = NCOLS - 1 - (int)(key & 0xFFFFFFFFu);
            if (ald32(&g_col_used[c])) {
                u64 best = 0ULL;
                const float4* row = (const float4*)(cost + (size_t)r * NCOLS);
                const u64* used = (const u64*)g_col_used;
                for (int k = tid; k < NCOLS / 4; k += 256) {
                    float4 v = row[k];
                    u64 w0 = ald64(&used[k * 2 + 0]);
                    u64 w1 = ald64(&used[k * 2 + 1]);
                    int c0 = k * 4;
                    if (!(u32)w0)         { u64 kk = ((u64)fsort(v.x) << 32) | (u32)(NCOLS - 1 - (c0 + 0)); if (kk > best) best = kk; }
                    if (!(u32)(w0 >> 32)) { u64 kk = ((u64)fsort(v.y) << 32) | (u32)(NCOLS - 1 - (c0 + 1)); if (kk > best) best = kk; }
                    if (!(u32)w1)         { u64 kk = ((u64)fsort(v.z) << 32) | (u32)(NCOLS - 1 - (c0 + 2)); if (kk > best) best = kk; }
                    if (!(u32)(w1 >> 32)) { u64 kk = ((u64)fsort(v.w) << 32) | (u32)(NCOLS - 1 - (c0 + 3)); if (kk > best) best = kk; }
                }
                u64 m = block_reduce_max(best, s_part);
                if (tid == 0) ast64(&g_rowbest[r], m);
            }
        }
        __syncthreads();
        if (tid == 0) s_nn[1] = 0;
        __syncthreads();
        for (int base = 0; base < n; base += 256) {
            bool win = false; int myr = -1, myc = -1;
            if (base + tid < n) {
                int r = s_rem[cur][base + tid];
                u64 key = ald64(&g_rowbest[r]);
                int c = NCOLS - 1 - (int)(key & 0xFFFFFFFFu);
                u64 mine = (key & 0xFFFFFFFF00000000ULL) | (u32)(NROWS - 1 - r);
                win = true;
                for (int j = 0; j < n; j++) {
                    int rj = s_rem[cur][j];
                    if (rj == r) continue;
                    float x = cost[(size_t)rj * NCOLS + c];
                    u64 kj = ((u64)fsort(x) << 32) | (u32)(NROWS - 1 - rj);
                    if (kj > mine) { win = false; break; }
                }
                myr = r; myc = c;
            }
            if (win) {
                ast32(&g_col_used[myc], 1);
                ast32(&g_row_assigned[myr], 1);
                out[NROWS + myr] = myc;
            }
            if (base + tid < n && !win) {
                int p = atomicAdd(&s_nn[1], 1);
                s_rem[cur ^ 1][p] = myr;
            }
        }
        __syncthreads();
        n = s_nn[1];
        cur ^= 1;
        __syncthreads();
    }
}

// ---------- Fused kernel: all phases, one dispatch, fence-free barriers ----
__global__ void __launch_bounds__(256, 4)
k_fused(const float* __restrict__ cost, int* __restrict__ out) {
    __shared__ u64 s_row[TROWS][4];
    __shared__ u64 s_part[4];
    __shared__ int s_rem[2][NROWS];
    __shared__ int s_nn[2];
    const int bid = blockIdx.x;
    const int tid = threadIdx.x;

    phase_scan(cost, bid, tid, s_row);
    grid_barrier(bid, tid);

    if (tid < 64) phase_commit(out, bid, tid);
    grid_barrier(bid, tid);

    phase_round(cost, out, 0, bid, tid, s_part);
    grid_barrier(bid, tid);

    phase_round(cost, out, 1, bid, tid, s_part);
    grid_barrier(bid, tid);

    if (bid == 0) phase_finish(cost, out, tid, s_rem, s_part, s_nn);
}

// ---------- DIAGNOSTIC kernels (this round only): phase attribution ----------
// Run AFTER k_fused; they rewrite scan partials idempotently / advance the
// monotone barrier gen - nothing that out depends on is re-read. Repeat
// factors sized so their dispatch dur beats the harness's 42us fills into
// the top-5 rocprof table: dur(k_scan6)/6 = scan phase; dur(k_bar64)/64 =
// barrier floor.
__global__ void __launch_bounds__(256, 4) k_scan6(const float* __restrict__ cost) {
    __shared__ u64 s_row[TROWS][4];
    for (int rep = 0; rep < 6; rep++) {
        phase_scan(cost, blockIdx.x, threadIdx.x, s_row);
        __syncthreads();   // protect s_row reuse across reps
    }
}
__global__ void __launch_bounds__(256, 4) k_bar64() {
    for (int rep = 0; rep < 64; rep++)
        grid_barrier(blockIdx.x, threadIdx.x);
}

extern "C" void kernel_launch(void* const* d_in, const int* in_sizes, int n_in,
                              void* d_out, int out_size, void* d_ws, size_t ws_size,
                              hipStream_t stream) {
    const float* cost = (const float*)d_in[0];
    int* out = (int*)d_out;
    k_fused<<<dim3(NBLK), dim3(256), 0, stream>>>(cost, out);
    // diagnostics (attribution round): harmless to correctness, removed next round
    k_scan6<<<dim3(NBLK), dim3(256), 0, stream>>>(cost);
    k_bar64<<<dim3(NBLK), dim3(256), 0, stream>>>();
}

// Round 7
// 141.634 us; speedup vs baseline: 3.7542x; 3.7542x over previous
//
#include <hip/hip_runtime.h>
#include <stdint.h>

#define NROWS 1024
#define NCOLS 16384
#define NRB 64        // row tiles (16 rows each)
#define NCB 16        // col tiles (1024 cols each)
#define TROWS 16      // rows per tile
#define NROUNDS 2
#define NBLK (NRB * NCB)   // 1024 blocks = 4/CU x 256 CU, all co-resident:
                           // launch_bounds(256,4) + small LDS -> 4 blocks/CU,
                           // plain launch (graph-capturable, round-4 verified).

#define NLEAF 64
#define LEAFSZ (NBLK / NLEAF)   // 16 arrivals per leaf

typedef unsigned long long u64;
typedef unsigned int u32;

// Persistent device state. Everything is written each call before being read.
__device__ u64 g_rowpart[NCB * NROWS];         // per col-tile row maxima
__device__ u64 g_colpart[(size_t)NRB * NCOLS]; // per row-tile col maxima (8 MB)
__device__ u64 g_rowbest[NROWS];               // key: (sortable<<32)|(NCOLS-1-col)
__device__ int g_col_used[NCOLS];
__device__ int g_row_assigned[NROWS];
__device__ int g_rem[2][NROWS];                // double-buffered remaining lists
__device__ int g_cnt[NROUNDS + 1];             // list counts per round

// Monotone (never-reset) tree-barrier counters; valid across launches/replays.
// ROUND-4/5 PROVEN layout (single gen line). The broadcast-release variant is
// shelved until the scan change is banked (round-6 container died unattributed;
// one risky change at a time).
__device__ int g_bar_leaf[NLEAF * 32];         // arrival counters, 128B/leaf
__device__ int g_bar_root;
__device__ int g_bar_gen;

// ---- RELAXED agent-scope accessors: device-coherent via MALL, NO cache
// maintenance ops (round-3 confirmed: removing wbl2/inv storms = 885->82us).
__device__ __forceinline__ u64 ald64(const u64* p) {
    return __hip_atomic_load((u64*)p, __ATOMIC_RELAXED, __HIP_MEMORY_SCOPE_AGENT);
}
__device__ __forceinline__ void ast64(u64* p, u64 v) {
    __hip_atomic_store(p, v, __ATOMIC_RELAXED, __HIP_MEMORY_SCOPE_AGENT);
}
__device__ __forceinline__ int ald32(const int* p) {
    return __hip_atomic_load((int*)p, __ATOMIC_RELAXED, __HIP_MEMORY_SCOPE_AGENT);
}
__device__ __forceinline__ void ast32(int* p, int v) {
    __hip_atomic_store(p, v, __ATOMIC_RELAXED, __HIP_MEMORY_SCOPE_AGENT);
}
__device__ __forceinline__ int aadd32(int* p, int v) {
    return __hip_atomic_fetch_add(p, v, __ATOMIC_RELAXED, __HIP_MEMORY_SCOPE_AGENT);
}

// Fence-free grid barrier (round-4/5 proven, 4.8us measured). All threads
// drain vmem (stores acked at MALL) -> syncthreads -> tid0 arrives via
// monotone leaf->root->gen counters at MALL; gen observers inherit causality.
__device__ __forceinline__ void grid_barrier(int bid, int tid) {
    asm volatile("s_waitcnt vmcnt(0)" ::: "memory");   // all threads drain
    __syncthreads();
    if (tid == 0) {
        int gen = ald32(&g_bar_gen);
        asm volatile("s_waitcnt vmcnt(0)" ::: "memory");  // snapshot bound
        int leaf = (bid & (NLEAF - 1)) * 32;
        int v = aadd32(&g_bar_leaf[leaf], 1);
        if ((v & (LEAFSZ - 1)) == LEAFSZ - 1) {           // leaf complete
            int u = aadd32(&g_bar_root, 1);
            if ((u & (NLEAF - 1)) == NLEAF - 1) {         // grid complete
                aadd32(&g_bar_gen, 1);
            }
        }
        while (ald32(&g_bar_gen) == gen) {
            __builtin_amdgcn_s_sleep(8);   // ~512cy nap, no cache ops
        }
    }
    __syncthreads();
    asm volatile("" ::: "memory");
}

// Monotone float32 -> uint32 mapping (preserves <):
__device__ __forceinline__ u32 fsort(float x) {
    u32 u = __float_as_uint(x);
    return u ^ ((u32)((int)u >> 31) | 0x80000000u);
}

__device__ __forceinline__ u64 wave_reduce_max(u64 v) {
    for (int off = 32; off; off >>= 1) {
        u64 o = __shfl_down(v, off);
        if (o > v) v = o;
    }
    return v;   // valid in lane 0
}

// blockDim == 256 (4 waves)
__device__ __forceinline__ u64 block_reduce_max(u64 v, u64* s_part) {
    v = wave_reduce_max(v);
    int wave = threadIdx.x >> 6;
    if ((threadIdx.x & 63) == 0) s_part[wave] = v;
    __syncthreads();
    u64 b = s_part[0];
    for (int w = 1; w < 4; w++) if (s_part[w] > b) b = s_part[w];
    __syncthreads();
    return b;
}

// Per-row scan helper: fold 4 cols into col-maxima (b0..b3, keyed by row) and
// produce the row-max candidate m (keyed by col).
__device__ __forceinline__ void scan_row(float4 v, int r, int c0,
                                         u64& b0, u64& b1, u64& b2, u64& b3,
                                         u64& m) {
    u32 rk = (u32)(NROWS - 1 - r);
    u64 k0 = ((u64)fsort(v.x) << 32) | rk; if (k0 > b0) b0 = k0;
    u64 k1 = ((u64)fsort(v.y) << 32) | rk; if (k1 > b1) b1 = k1;
    u64 k2 = ((u64)fsort(v.z) << 32) | rk; if (k2 > b2) b2 = k2;
    u64 k3 = ((u64)fsort(v.w) << 32) | rk; if (k3 > b3) b3 = k3;
    u64 m0 = ((u64)fsort(v.x) << 32) | (u32)(NCOLS - 1 - (c0 + 0));
    u64 m1 = ((u64)fsort(v.y) << 32) | (u32)(NCOLS - 1 - (c0 + 1));
    u64 m2 = ((u64)fsort(v.z) << 32) | (u32)(NCOLS - 1 - (c0 + 2));
    u64 m3 = ((u64)fsort(v.w) << 32) | (u32)(NCOLS - 1 - (c0 + 3));
    m = m0; if (m1 > m) m = m1; if (m2 > m) m = m2; if (m3 > m) m = m3;
}

// ---------- Phase 1: tile scan. 16 rows x 1024 cols per block ----------
// Row-max via LDS TRANSPOSE REDUCE, not wave shuffles. Round-5 attribution:
// scan = 24.5us MALL-resident (2.5x its 10us memory roofline) because the
// shuffle reduce issued 192 ds_bpermute_b32 per thread through the CU's
// single LDS pipe. Transpose scheme: each thread writes its per-row
// candidates to s_cand[row][tid], 16 threads/row reduce 16 strided entries
// each, 16 threads finish -> ~35 LDS ops/thread. Done in TWO 8-row passes
// through a [8][256] buffer (16KB) to keep total LDS at 18.6KB: round-6's
// 35KB single-pass version never ran (container died, unattributed); this
// stays in the LDS regime proven to hold 4 blocks/CU co-residency.
__device__ __forceinline__ void phase_scan(const float* __restrict__ cost,
                                           int fb, int tid,
                                           u64 (*s_cand)[256],
                                           u64 (*s_p2)[17]) {
    const int cb = fb & (NCB - 1);
    const int rb = fb >> 4;
    const int cbase = cb * 1024;
    const int r0 = rb * TROWS;
    const int c0 = cbase + tid * 4;

    if (rb == 0) {     // init: each cb-block zeroes its col_used slice (MALL)
        ast64((u64*)(g_col_used + cbase) + tid * 2 + 0, 0ULL);
        ast64((u64*)(g_col_used + cbase) + tid * 2 + 1, 0ULL);
        if (cb == 0 && tid <= NROUNDS) ast32(&g_cnt[tid], 0);
    }

    u64 b0 = 0, b1 = 0, b2 = 0, b3 = 0;
    for (int half = 0; half < 2; ++half) {
        const int rbase = r0 + half * 8;
        for (int g = 0; g < 8; g += 4) {
            const float* base = cost + (size_t)(rbase + g) * NCOLS + c0;
            float4 v0 = *(const float4*)(base);
            float4 v1 = *(const float4*)(base + NCOLS);
            float4 v2 = *(const float4*)(base + 2 * NCOLS);
            float4 v3 = *(const float4*)(base + 3 * NCOLS);
            u64 m0, m1, m2, m3;
            scan_row(v0, rbase + g + 0, c0, b0, b1, b2, b3, m0);
            scan_row(v1, rbase + g + 1, c0, b0, b1, b2, b3, m1);
            scan_row(v2, rbase + g + 2, c0, b0, b1, b2, b3, m2);
            scan_row(v3, rbase + g + 3, c0, b0, b1, b2, b3, m3);
            s_cand[g + 0][tid] = m0;
            s_cand[g + 1][tid] = m1;
            s_cand[g + 2][tid] = m2;
            s_cand[g + 3][tid] = m3;
        }
        __syncthreads();
        if (tid < 128) {   // stage 1: 16 threads/row, stride-16 chains
            int r = tid >> 4, j = tid & 15;
            u64 m = s_cand[r][j];
            #pragma unroll
            for (int i = 1; i < 16; i++) {
                u64 o = s_cand[r][j + 16 * i];
                if (o > m) m = o;
            }
            s_p2[half * 8 + r][j] = m;
        }
        __syncthreads();   // protects s_cand reuse (half 1) and s_p2 for stage 2
    }
    size_t cp = (size_t)rb * NCOLS + c0;
    ast64(&g_colpart[cp + 0], b0);
    ast64(&g_colpart[cp + 1], b1);
    ast64(&g_colpart[cp + 2], b2);
    ast64(&g_colpart[cp + 3], b3);
    if (tid < TROWS) {   // stage 2: one thread per row
        u64 m = s_p2[tid][0];
        #pragma unroll
        for (int i = 1; i < 16; i++) {
            u64 o = s_p2[tid][i];
            if (o > m) m = o;
        }
        ast64(&g_rowpart[cb * NROWS + (r0 + tid)], m);
    }
}

// ---------- Phase 2: mutual-best commit. One wave per row r ----------
__device__ __forceinline__ void phase_commit(int* __restrict__ out, int r, int lane) {
    u64 v = ald64(&g_rowpart[(lane & 15) * NROWS + r]);
    u64 key = wave_reduce_max(v);
    key = __shfl(key, 0);                       // broadcast
    int c = NCOLS - 1 - (int)(key & 0xFFFFFFFFu);

    u64 cp = ald64(&g_colpart[(size_t)lane * NCOLS + c]);
    u64 colmax = wave_reduce_max(cp);           // lane 0

    if (lane == 0) {
        ast64(&g_rowbest[r], key);
        out[r] = r;                             // identity row indices
        u64 mk = (key & 0xFFFFFFFF00000000ULL) | (u32)(NROWS - 1 - r);
        if (colmax == mk) {                     // mutual best -> commit
            ast32(&g_col_used[c], 1);
            ast32(&g_row_assigned[r], 1);
            out[NROWS + r] = c;
        } else {
            ast32(&g_row_assigned[r], 0);
            int p = aadd32(&g_cnt[0], 1);
            ast32(&g_rem[0][p], r);
        }
    }
}

// ---------- Per-round phase (256 threads, block = row r) ----------
__device__ __forceinline__ void phase_round(const float* __restrict__ cost,
                                            int* __restrict__ out, int t, int r,
                                            int tid, u64* s_part) {
    if (ald32(&g_row_assigned[r])) return;   // uniform across block

    u64 key = ald64(&g_rowbest[r]);
    int c = NCOLS - 1 - (int)(key & 0xFFFFFFFFu);
    if (ald32(&g_col_used[c])) {      // stale -> rescan excluding used cols
        u64 best = 0ULL;
        const float4* row = (const float4*)(cost + (size_t)r * NCOLS);
        const u64* used = (const u64*)g_col_used;
        for (int k = tid; k < NCOLS / 4; k += 256) {
            float4 v = row[k];
            u64 w0 = ald64(&used[k * 2 + 0]);   // cols c0, c0+1
            u64 w1 = ald64(&used[k * 2 + 1]);   // cols c0+2, c0+3
            int c0 = k * 4;
            if (!(u32)w0)         { u64 kk = ((u64)fsort(v.x) << 32) | (u32)(NCOLS - 1 - (c0 + 0)); if (kk > best) best = kk; }
            if (!(u32)(w0 >> 32)) { u64 kk = ((u64)fsort(v.y) << 32) | (u32)(NCOLS - 1 - (c0 + 1)); if (kk > best) best = kk; }
            if (!(u32)w1)         { u64 kk = ((u64)fsort(v.z) << 32) | (u32)(NCOLS - 1 - (c0 + 2)); if (kk > best) best = kk; }
            if (!(u32)(w1 >> 32)) { u64 kk = ((u64)fsort(v.w) << 32) | (u32)(NCOLS - 1 - (c0 + 3)); if (kk > best) best = kk; }
        }
        key = block_reduce_max(best, s_part);
        if (tid == 0) ast64(&g_rowbest[r], key);
        c = NCOLS - 1 - (int)(key & 0xFFFFFFFFu);
    }

    int n = ald32(&g_cnt[t]);
    const int* list = g_rem[t & 1];
    u64 mine = (key & 0xFFFFFFFF00000000ULL) | (u32)(NROWS - 1 - r);
    u64 mx = 0ULL;
    for (int j = tid; j < n; j += 256) {
        int rj = ald32(&list[j]);
        if (rj != r) {
            float x = cost[(size_t)rj * NCOLS + c];
            u64 kj = ((u64)fsort(x) << 32) | (u32)(NROWS - 1 - rj);
            if (kj > mx) mx = kj;
        }
    }
    mx = block_reduce_max(mx, s_part);
    if (tid == 0) {
        if (mine > mx) {              // unique max at col c among survivors
            ast32(&g_col_used[c], 1);
            ast32(&g_row_assigned[r], 1);
            out[NROWS + r] = c;
        } else {
            int p = aadd32(&g_cnt[t + 1], 1);
            ast32(&g_rem[(t + 1) & 1][p], r);
        }
    }
}

// ---------- Final serial cleanup, single block of 256 ----------
__device__ __forceinline__ void phase_finish(const float* __restrict__ cost,
                                             int* __restrict__ out, int tid,
                                             int (*s_rem)[NROWS], u64* s_part,
                                             int* s_nn) {
    if (tid == 0) s_nn[0] = ald32(&g_cnt[NROUNDS]);
    __syncthreads();
    int n = s_nn[0];
    if (n == 0) return;
    for (int i = tid; i < n; i += 256) s_rem[0][i] = ald32(&g_rem[NROUNDS & 1][i]);
    __syncthreads();
    int cur = 0;
    while (n > 0) {
        for (int i = 0; i < n; i++) {
            int r = s_rem[cur][i];
            u64 key = ald64(&g_rowbest[r]);
            int c = NCOLS - 1 - (int)(key & 0xFFFFFFFFu);
            if (ald32(&g_col_used[c])) {
                u64 best = 0ULL;
                const float4* row = (const float4*)(cost + (size_t)r * NCOLS);
                const u64* used = (const u64*)g_col_used;
                for (int k = tid; k < NCOLS / 4; k += 256) {
                    float4 v = row[k];
                    u64 w0 = ald64(&used[k * 2 + 0]);
                    u64 w1 = ald64(&used[k * 2 + 1]);
                    int c0 = k * 4;
                    if (!(u32)w0)         { u64 kk = ((u64)fsort(v.x) << 32) | (u32)(NCOLS - 1 - (c0 + 0)); if (kk > best) best = kk; }
                    if (!(u32)(w0 >> 32)) { u64 kk = ((u64)fsort(v.y) << 32) | (u32)(NCOLS - 1 - (c0 + 1)); if (kk > best) best = kk; }
                    if (!(u32)w1)         { u64 kk = ((u64)fsort(v.z) << 32) | (u32)(NCOLS - 1 - (c0 + 2)); if (kk > best) best = kk; }
                    if (!(u32)(w1 >> 32)) { u64 kk = ((u64)fsort(v.w) << 32) | (u32)(NCOLS - 1 - (c0 + 3)); if (kk > best) best = kk; }
                }
                u64 m = block_reduce_max(best, s_part);
                if (tid == 0) ast64(&g_rowbest[r], m);
            }
        }
        __syncthreads();
        if (tid == 0) s_nn[1] = 0;
        __syncthreads();
        for (int base = 0; base < n; base += 256) {
            bool win = false; int myr = -1, myc = -1;
            if (base + tid < n) {
                int r = s_rem[cur][base + tid];
                u64 key = ald64(&g_rowbest[r]);
                int c = NCOLS - 1 - (int)(key & 0xFFFFFFFFu);
                u64 mine = (key & 0xFFFFFFFF00000000ULL) | (u32)(NROWS - 1 - r);
                win = true;
                for (int j = 0; j < n; j++) {
                    int rj = s_rem[cur][j];
                    if (rj == r) continue;
                    float x = cost[(size_t)rj * NCOLS + c];
                    u64 kj = ((u64)fsort(x) << 32) | (u32)(NROWS - 1 - rj);
                    if (kj > mine) { win = false; break; }
                }
                myr = r; myc = c;
            }
            if (win) {
                ast32(&g_col_used[myc], 1);
                ast32(&g_row_assigned[myr], 1);
                out[NROWS + myr] = myc;
            }
            if (base + tid < n && !win) {
                int p = atomicAdd(&s_nn[1], 1);
                s_rem[cur ^ 1][p] = myr;
            }
        }
        __syncthreads();
        n = s_nn[1];
        cur ^= 1;
        __syncthreads();
    }
}

// ---------- Fused kernel: all phases, one dispatch, fence-free barriers ----
// LDS budget: s_cand 16384 + s_p2 2176 + s_part 32 + s_nn 8 = 18600 B.
// 4 blocks/CU x 18.6KB = 74.4KB << 160KB/CU: co-residency holds with wide
// margin (violating it would deadlock the spin barrier). finish's s_rem
// (8KB int[2][1024]) aliases s_cand (scan long done by then).
__global__ void __launch_bounds__(256, 4)
k_fused(const float* __restrict__ cost, int* __restrict__ out) {
    __shared__ u64 s_cand[8][256];
    __shared__ u64 s_p2[TROWS][17];
    __shared__ u64 s_part[4];
    __shared__ int s_nn[2];
    const int bid = blockIdx.x;
    const int tid = threadIdx.x;

    phase_scan(cost, bid, tid, s_cand, s_p2);
    grid_barrier(bid, tid);

    if (tid < 64) phase_commit(out, bid, tid);
    grid_barrier(bid, tid);

    phase_round(cost, out, 0, bid, tid, s_part);
    grid_barrier(bid, tid);

    phase_round(cost, out, 1, bid, tid, s_part);
    grid_barrier(bid, tid);

    if (bid == 0)
        phase_finish(cost, out, tid,
                     reinterpret_cast<int(*)[NROWS]>(&s_cand[0][0]),
                     s_part, s_nn);
}

extern "C" void kernel_launch(void* const* d_in, const int* in_sizes, int n_in,
                              void* d_out, int out_size, void* d_ws, size_t ws_size,
                              hipStream_t stream) {
    const float* cost = (const float*)d_in[0];
    int* out = (int*)d_out;
    k_fused<<<dim3(NBLK), dim3(256), 0, stream>>>(cost, out);
}